// Round 2
// baseline (444.161 us; speedup 1.0000x reference)
//
#include <hip/hip_runtime.h>
#include <hip/hip_bf16.h>

// Problem: B=256, IN=512, OUT=512
//   y_mean = x_mean @ A_mean + b_mean                       [B,OUT]
//   y_var  = diag_embed( (diag(x_var)+x_mean^2) @ A_var
//                        + diag(A^T Cov A) + b_var )        [B,OUT,OUT]
// term2[b,o] = sum_i A[i,o] * (x_var[b] @ A)[i,o]  -> stacked GEMM + weighted colsum

typedef __bf16 bf16x8 __attribute__((ext_vector_type(8)));
typedef float f32x4 __attribute__((ext_vector_type(4)));

__device__ inline ushort f2bf(float f) {
    union { float f; unsigned u; } x; x.f = f;
    unsigned u = x.u + 0x7fffu + ((x.u >> 16) & 1u);   // RNE
    return (ushort)(u >> 16);
}

// ---------------- kernel 1: A_mean -> bf16, transposed: abt[o][j] ----------------
__global__ void k_prep_at(const float* __restrict__ am, ushort* __restrict__ abt) {
    __shared__ ushort tile[64][65];
    int t = threadIdx.x;
    int r0 = (blockIdx.x >> 3) * 64;   // j block
    int c0 = (blockIdx.x & 7) * 64;    // o block
    #pragma unroll
    for (int q = 0; q < 16; ++q) {
        int idx = q * 256 + t;
        int r = idx >> 6, c = idx & 63;
        tile[r][c] = f2bf(am[(r0 + r) * 512 + c0 + c]);
    }
    __syncthreads();
    #pragma unroll
    for (int q = 0; q < 16; ++q) {
        int idx = q * 256 + t;
        int ro = idx >> 6, co = idx & 63;          // out row o=c0+ro, col j=r0+co
        abt[(c0 + ro) * 512 + r0 + co] = tile[co][ro];
    }
}

// ---------------- kernel 2: xx[b][i] = x_var[b,i,i] + x_mean^2 ----------------
__global__ void k_diag(const float* __restrict__ xv, const float* __restrict__ xm,
                       float* __restrict__ xx) {
    int idx = blockIdx.x * 256 + threadIdx.x;     // 0..131071  (b*512+i)
    int b = idx >> 9, i = idx & 511;
    float m = xm[idx];
    xx[idx] = xv[(long)b * 262144 + i * 513] + m * m;
}

// ---------------- kernel 3: y_mean and pd = term1 + b_var ----------------
__global__ void k_mean_t1(const float* __restrict__ xm, const float* __restrict__ xx,
                          const float* __restrict__ am, const float* __restrict__ av,
                          const float* __restrict__ bm, const float* __restrict__ bv,
                          float* __restrict__ ymean, float* __restrict__ pd) {
    __shared__ float xmS[8][512];
    __shared__ float xxS[8][512];
    int t = threadIdx.x;
    int bt = blockIdx.x >> 4;       // 0..31
    int ot = blockIdx.x & 15;       // 0..15
    int b0 = bt * 8, o0 = ot * 32;
    #pragma unroll
    for (int q = 0; q < 16; ++q) {
        int idx = q * 256 + t;      // 0..4095
        int bb = idx >> 9, i = idx & 511;
        xmS[bb][i] = xm[(b0 + bb) * 512 + i];
        xxS[bb][i] = xx[(b0 + bb) * 512 + i];
    }
    __syncthreads();
    int bb = t >> 5, oo = t & 31;
    int b = b0 + bb, o = o0 + oo;
    float ym = bm[o], t1 = bv[o];
    for (int i = 0; i < 512; ++i) {
        float a  = am[i * 512 + o];
        float va = av[i * 512 + o];
        ym = fmaf(xmS[bb][i], a,  ym);
        t1 = fmaf(xxS[bb][i], va, t1);
    }
    ymean[b * 512 + o] = ym;
    pd[b * 512 + o]    = t1;
}

// ---------------- kernel 4: big MFMA GEMM + weighted colsum -> p2[b][msub][o] ----------------
__global__ __launch_bounds__(256, 2) void k_gemm2(
        const float*  __restrict__ xv,    // Xflat [131072][512] f32
        const ushort* __restrict__ abt,   // A^T bf16 [o][j]
        const float*  __restrict__ amean, // A f32 [j][o]
        float* __restrict__ p2)           // [256][4][512]
{
    __shared__ ushort ldsX[2][8192];      // [buf][128 rows * 64 bf16]  16KB each
    __shared__ ushort ldsA[2][8192];
    __shared__ float  red[2][128];

    int t = threadIdx.x;
    int lane = t & 63;
    int wave = t >> 6;
    int wm = wave >> 1, wn = wave & 1;

    int mtile = blockIdx.x >> 2;          // 0..1023
    int ntile = blockIdx.x & 3;
    long m0 = (long)mtile * 128;
    int  n0 = ntile * 128;

    f32x4 acc[4][4];
    #pragma unroll
    for (int a = 0; a < 4; ++a)
        #pragma unroll
        for (int bqq = 0; bqq < 4; ++bqq)
            acc[a][bqq] = (f32x4){0.f, 0.f, 0.f, 0.f};

    float4 xr[8]; int4 ar[4];

    auto loadX = [&](int k0) {
        #pragma unroll
        for (int q = 0; q < 8; ++q) {
            int idx = q * 256 + t;
            int r = idx >> 4, c4 = idx & 15;
            xr[q] = *(const float4*)(xv + (m0 + r) * 512 + k0 + c4 * 4);
        }
    };
    auto loadA = [&](int k0) {
        #pragma unroll
        for (int q = 0; q < 4; ++q) {
            int idx = q * 256 + t;              // 0..1023
            int r = idx >> 3, c8 = idx & 7;     // 128 rows x 8 chunks of 8 bf16
            ar[q] = *(const int4*)(abt + (n0 + r) * 512 + k0 + c8 * 8);
        }
    };
    auto writeX = [&](ushort* dst) {
        #pragma unroll
        for (int q = 0; q < 8; ++q) {
            int idx = q * 256 + t;
            int r = idx >> 4, c4 = idx & 15;
            ushort4 u;
            u.x = f2bf(xr[q].x); u.y = f2bf(xr[q].y);
            u.z = f2bf(xr[q].z); u.w = f2bf(xr[q].w);
            *(ushort4*)((char*)dst + r * 128 + ((c4 * 8) ^ ((r & 7) << 4))) = u;
        }
    };
    auto writeA = [&](ushort* dst) {
        #pragma unroll
        for (int q = 0; q < 4; ++q) {
            int idx = q * 256 + t;
            int r = idx >> 3, c8 = idx & 7;
            *(int4*)((char*)dst + r * 128 + ((c8 * 16) ^ ((r & 7) << 4))) = ar[q];
        }
    };
    auto compute = [&](const ushort* xs, const ushort* as) {
        #pragma unroll
        for (int kc = 0; kc < 2; ++kc) {
            bf16x8 af[4], bfr[4];
            int kb = kc * 64 + (lane >> 4) * 16;      // byte col within row
            #pragma unroll
            for (int mf = 0; mf < 4; ++mf) {
                int r = wm * 64 + mf * 16 + (lane & 15);
                af[mf] = *(const bf16x8*)((const char*)xs + r * 128 + (kb ^ ((r & 7) << 4)));
            }
            #pragma unroll
            for (int nf = 0; nf < 4; ++nf) {
                int r = wn * 64 + nf * 16 + (lane & 15);
                bfr[nf] = *(const bf16x8*)((const char*)as + r * 128 + (kb ^ ((r & 7) << 4)));
            }
            #pragma unroll
            for (int mf = 0; mf < 4; ++mf)
                #pragma unroll
                for (int nf = 0; nf < 4; ++nf)
                    acc[mf][nf] = __builtin_amdgcn_mfma_f32_16x16x32_bf16(
                        af[mf], bfr[nf], acc[mf][nf], 0, 0, 0);
        }
    };

    // prologue
    loadX(0); loadA(0);
    writeX(ldsX[0]); writeA(ldsA[0]);
    __syncthreads();

    int cur = 0;
    for (int ks = 0; ks < 8; ++ks) {
        if (ks < 7) { loadX((ks + 1) * 64); loadA((ks + 1) * 64); }  // issue early (T14)
        compute(ldsX[cur], ldsA[cur]);
        if (ks < 7) { writeX(ldsX[cur ^ 1]); writeA(ldsA[cur ^ 1]); }
        __syncthreads();
        cur ^= 1;
    }

    // epilogue: weighted colsum  term2_partial[o] = sum_rows A[i,o]*C[i,o]
    int msub = mtile & 3;
    int b = mtile >> 2;
    #pragma unroll
    for (int nf = 0; nf < 4; ++nf) {
        float p = 0.f;
        int o = n0 + wn * 64 + nf * 16 + (lane & 15);
        #pragma unroll
        for (int mf = 0; mf < 4; ++mf) {
            #pragma unroll
            for (int j = 0; j < 4; ++j) {
                int i = msub * 128 + wm * 64 + mf * 16 + ((lane >> 4) * 4) + j;
                p += acc[mf][nf][j] * amean[i * 512 + o];
            }
        }
        p += __shfl_xor(p, 16, 64);
        p += __shfl_xor(p, 32, 64);
        if (lane < 16) red[wm][wn * 64 + nf * 16 + lane] = p;
    }
    __syncthreads();
    if (t < 128) {
        float v = red[0][t] + red[1][t];
        p2[((long)b * 4 + msub) * 512 + n0 + t] = v;
    }
}

// ---------------- kernel 5: write y_var = diag_embed(pd + sum(p2)) ----------------
__global__ void k_fill(const float* __restrict__ pd, const float* __restrict__ p2,
                       float* __restrict__ yvar) {
    int t = threadIdx.x;
    long base = (long)blockIdx.x * 8;            // 8 rows per block
    #pragma unroll
    for (int q = 0; q < 4; ++q) {
        int idx = q * 256 + t;                   // 0..1023
        int rl = idx >> 7, f4 = idx & 127;
        long gr = base + rl;                     // b*512 + o
        int b = (int)(gr >> 9), o = (int)(gr & 511);
        float4 val = make_float4(0.f, 0.f, 0.f, 0.f);
        if ((o >> 2) == f4) {
            long pb = (long)b * 2048 + o;
            float v = pd[gr] + p2[pb] + p2[pb + 512] + p2[pb + 1024] + p2[pb + 1536];
            ((float*)&val)[o & 3] = v;
        }
        *(float4*)(yvar + gr * 512 + (long)f4 * 4) = val;
    }
}

extern "C" void kernel_launch(void* const* d_in, const int* in_sizes, int n_in,
                              void* d_out, int out_size, void* d_ws, size_t ws_size,
                              hipStream_t stream) {
    const float* x_mean = (const float*)d_in[0];   // [256,512]
    const float* x_var  = (const float*)d_in[1];   // [256,512,512]
    const float* A_mean = (const float*)d_in[2];   // [512,512]
    const float* A_var  = (const float*)d_in[3];   // [512,512]
    const float* b_mean = (const float*)d_in[4];   // [512]
    const float* b_var  = (const float*)d_in[5];   // [512]

    float* ymean = (float*)d_out;                  // [256,512]
    float* yvar  = (float*)d_out + 131072;         // [256,512,512]

    char* ws = (char*)d_ws;
    ushort* abt = (ushort*)ws;                     // 512*512 bf16   (512 KB)
    float*  pd  = (float*)(ws + 512 * 1024);       // [256,512]      (512 KB)
    float*  p2  = (float*)(ws + 1024 * 1024);      // [256,4,512]    (2 MB)
    float*  xx  = (float*)(ws + 3 * 1024 * 1024);  // [256,512]      (512 KB)

    k_prep_at<<<64, 256, 0, stream>>>(A_mean, abt);
    k_diag<<<512, 256, 0, stream>>>(x_var, x_mean, xx);
    k_mean_t1<<<512, 256, 0, stream>>>(x_mean, xx, A_mean, A_var, b_mean, b_var,
                                       ymean, pd);
    k_gemm2<<<4096, 256, 0, stream>>>(x_var, abt, A_mean, p2);
    k_fill<<<16384, 256, 0, stream>>>(pd, p2, yvar);
}

// Round 3
// 324.091 us; speedup vs baseline: 1.3705x; 1.3705x over previous
//
#include <hip/hip_runtime.h>
#include <hip/hip_bf16.h>

// B=256, IN=512, OUT=512
//   y_mean = x_mean @ A_mean + b_mean
//   y_var  = diag_embed( (diag(x_var)+x_mean^2) @ A_var + diag(A^T Cov A) + b_var )
// term2[b,o] = sum_i A[i,o] * (x_var[b] @ A)[i,o]  -> stacked GEMM + weighted colsum
//
// Tile images: both GEMM operands pre-converted to bf16 and stored as 16KB
// "LDS images" (row r*128B + XOR-swizzled 16B chunks) so k_gemm2 stages them
// with linear global_load_lds (no reg staging, no spills).

typedef __bf16 bf16x8 __attribute__((ext_vector_type(8)));
typedef float f32x4 __attribute__((ext_vector_type(4)));

__device__ inline ushort f2bf(float f) {
    union { float f; unsigned u; } x; x.f = f;
    unsigned u = x.u + 0x7fffu + ((x.u >> 16) & 1u);   // RNE
    return (ushort)(u >> 16);
}

__device__ inline void gload16(const void* g, void* l) {
    __builtin_amdgcn_global_load_lds(
        (const __attribute__((address_space(1))) void*)g,
        (__attribute__((address_space(3))) void*)l, 16, 0, 0);
}

// ---- kernel 1: A_mean -> bf16 A^T tile images: abt[(nt*8+ks)*16KB] ----
// image byte = r*128 + ((c ^ (r&7))*16) + e*2 ; value = A[ks*64+c*8+e][nt*128+r]
__global__ void k_prep_at(const float* __restrict__ am, ushort* __restrict__ abt) {
    int C = blockIdx.x * 256 + threadIdx.x;   // chunk id 0..32767
    int nt = C >> 13;
    int L  = C & 8191;
    int ks = L >> 10;
    int rem = L & 1023;
    int r = rem >> 3, cs = rem & 7;
    int c = cs ^ (r & 7);
    int o = nt * 128 + r;
    int j0 = ks * 64 + c * 8;
    ushort u[8];
    #pragma unroll
    for (int e = 0; e < 8; ++e) u[e] = f2bf(am[(j0 + e) * 512 + o]);
    *(int4*)(abt + (long)C * 8) = *(int4*)u;
}

// ---- kernel 2: x_var f32 -> bf16 tile images xbf + diag extraction ----
__global__ void k_conv(const float* __restrict__ xv, const float* __restrict__ xm,
                       ushort* __restrict__ xbf, float* __restrict__ xx) {
    int mtile = blockIdx.x;                   // 0..1023 (128-row block of Xflat)
    int t = threadIdx.x;
    long ibase = (long)mtile * 65536;         // ushort offset of this 128KB image set
    #pragma unroll 8
    for (int it = 0; it < 32; ++it) {
        int L = it * 256 + t;                 // chunk 0..8191
        int ks = L >> 10;
        int rem = L & 1023;
        int r = rem >> 3, cs = rem & 7;
        int c = cs ^ (r & 7);
        int R = mtile * 128 + r;              // Xflat row = b*512 + i
        int j0 = ks * 64 + c * 8;
        const float* src = xv + (long)R * 512 + j0;
        float4 v0 = *(const float4*)src;
        float4 v1 = *(const float4*)(src + 4);
        ushort u[8];
        u[0] = f2bf(v0.x); u[1] = f2bf(v0.y); u[2] = f2bf(v0.z); u[3] = f2bf(v0.w);
        u[4] = f2bf(v1.x); u[5] = f2bf(v1.y); u[6] = f2bf(v1.z); u[7] = f2bf(v1.w);
        *(int4*)(xbf + ibase + (long)L * 8) = *(int4*)u;
        int d = (R & 511) - j0;               // diagonal j == i ?
        if (d >= 0 && d < 8) {
            float val = d == 0 ? v0.x : d == 1 ? v0.y : d == 2 ? v0.z : d == 3 ? v0.w
                      : d == 4 ? v1.x : d == 5 ? v1.y : d == 6 ? v1.z : v1.w;
            float m = xm[R];
            xx[R] = val + m * m;
        }
    }
}

// ---- kernel 3: y_mean and pd = term1 + b_var ----
__global__ void k_mean_t1(const float* __restrict__ xm, const float* __restrict__ xx,
                          const float* __restrict__ am, const float* __restrict__ av,
                          const float* __restrict__ bm, const float* __restrict__ bv,
                          float* __restrict__ ymean, float* __restrict__ pd) {
    __shared__ float xmS[8][512];
    __shared__ float xxS[8][512];
    int t = threadIdx.x;
    int bt = blockIdx.x >> 4;
    int ot = blockIdx.x & 15;
    int b0 = bt * 8, o0 = ot * 32;
    #pragma unroll
    for (int q = 0; q < 16; ++q) {
        int idx = q * 256 + t;
        int bb = idx >> 9, i = idx & 511;
        xmS[bb][i] = xm[(b0 + bb) * 512 + i];
        xxS[bb][i] = xx[(b0 + bb) * 512 + i];
    }
    __syncthreads();
    int bb = t >> 5, oo = t & 31;
    int b = b0 + bb, o = o0 + oo;
    float ym = bm[o], t1 = bv[o];
    for (int i = 0; i < 512; ++i) {
        float a  = am[i * 512 + o];
        float va = av[i * 512 + o];
        ym = fmaf(xmS[bb][i], a,  ym);
        t1 = fmaf(xxS[bb][i], va, t1);
    }
    ymean[b * 512 + o] = ym;
    pd[b * 512 + o]    = t1;
}

// ---- kernel 4: MFMA GEMM (gload_lds both operands) + weighted colsum ----
__global__ __launch_bounds__(256, 2) void k_gemm2(
        const ushort* __restrict__ xbf,   // tile images [1024][8][16KB]
        const ushort* __restrict__ abt,   // tile images [4][8][16KB]
        const float*  __restrict__ amean, // A f32 [j][o]
        float* __restrict__ p2)           // [256][4][512]
{
    __shared__ ushort ldsX[2][8192];
    __shared__ ushort ldsA[2][8192];
    __shared__ float  red[2][128];

    int t = threadIdx.x;
    int lane = t & 63;
    int wave = t >> 6;
    int wm = wave >> 1, wn = wave & 1;

    int bid = blockIdx.x;
    int swz = (bid & 7) * 512 + (bid >> 3);   // bijective XCD swizzle (4096%8==0)
    int mtile = swz >> 2;                     // 0..1023
    int ntile = swz & 3;
    int n0 = ntile * 128;

    f32x4 acc[4][4];
    #pragma unroll
    for (int a = 0; a < 4; ++a)
        #pragma unroll
        for (int bq = 0; bq < 4; ++bq)
            acc[a][bq] = (f32x4){0.f, 0.f, 0.f, 0.f};

    const char* xsrc = (const char*)xbf + (long)mtile * 131072 + t * 16;
    const char* asrc = (const char*)abt + (long)ntile * 131072 + t * 16;

    auto stage = [&](int buf, int ks) {
        const char* xs = xsrc + ks * 16384;
        const char* as = asrc + ks * 16384;
        char* xd = (char*)ldsX[buf] + wave * 1024;
        char* ad = (char*)ldsA[buf] + wave * 1024;
        #pragma unroll
        for (int q = 0; q < 4; ++q) {
            gload16(xs + q * 4096, xd + q * 4096);
            gload16(as + q * 4096, ad + q * 4096);
        }
    };

    auto compute = [&](const ushort* xs, const ushort* as) {
        #pragma unroll
        for (int kc = 0; kc < 2; ++kc) {
            bf16x8 af[4], bfr[4];
            int kb = kc * 64 + (lane >> 4) * 16;
            #pragma unroll
            for (int mf = 0; mf < 4; ++mf) {
                int r = wm * 64 + mf * 16 + (lane & 15);
                af[mf] = *(const bf16x8*)((const char*)xs + r * 128 + (kb ^ ((r & 7) << 4)));
            }
            #pragma unroll
            for (int nf = 0; nf < 4; ++nf) {
                int r = wn * 64 + nf * 16 + (lane & 15);
                bfr[nf] = *(const bf16x8*)((const char*)as + r * 128 + (kb ^ ((r & 7) << 4)));
            }
            #pragma unroll
            for (int mf = 0; mf < 4; ++mf)
                #pragma unroll
                for (int nf = 0; nf < 4; ++nf)
                    acc[mf][nf] = __builtin_amdgcn_mfma_f32_16x16x32_bf16(
                        af[mf], bfr[nf], acc[mf][nf], 0, 0, 0);
        }
    };

    stage(0, 0);
    __syncthreads();
    int cur = 0;
    for (int ks = 0; ks < 8; ++ks) {
        if (ks < 7) stage(cur ^ 1, ks + 1);
        compute(ldsX[cur], ldsA[cur]);
        __syncthreads();
        cur ^= 1;
    }

    // epilogue: term2_partial[o] = sum_rows A[i,o]*C[i,o]
    int msub = mtile & 3;
    int b = mtile >> 2;
    #pragma unroll
    for (int nf = 0; nf < 4; ++nf) {
        float p = 0.f;
        int o = n0 + wn * 64 + nf * 16 + (lane & 15);
        #pragma unroll
        for (int mf = 0; mf < 4; ++mf) {
            #pragma unroll
            for (int j = 0; j < 4; ++j) {
                int i = msub * 128 + wm * 64 + mf * 16 + ((lane >> 4) * 4) + j;
                p += acc[mf][nf][j] * amean[i * 512 + o];
            }
        }
        p += __shfl_xor(p, 16, 64);
        p += __shfl_xor(p, 32, 64);
        if (lane < 16) red[wm][wn * 64 + nf * 16 + lane] = p;
    }
    __syncthreads();
    if (t < 128) {
        float v = red[0][t] + red[1][t];
        p2[((long)b * 4 + msub) * 512 + n0 + t] = v;
    }
}

// ---- kernel 5: y_var = diag_embed(pd + sum(p2)) ----
__global__ void k_fill(const float* __restrict__ pd, const float* __restrict__ p2,
                       float* __restrict__ yvar) {
    int t = threadIdx.x;
    long base = (long)blockIdx.x * 8;
    #pragma unroll
    for (int q = 0; q < 4; ++q) {
        int idx = q * 256 + t;
        int rl = idx >> 7, f4 = idx & 127;
        long gr = base + rl;                  // b*512 + o
        int b = (int)(gr >> 9), o = (int)(gr & 511);
        float4 val = make_float4(0.f, 0.f, 0.f, 0.f);
        if ((o >> 2) == f4) {
            long pb = (long)b * 2048 + o;
            float v = pd[gr] + p2[pb] + p2[pb + 512] + p2[pb + 1024] + p2[pb + 1536];
            ((float*)&val)[o & 3] = v;
        }
        *(float4*)(yvar + gr * 512 + (long)f4 * 4) = val;
    }
}

extern "C" void kernel_launch(void* const* d_in, const int* in_sizes, int n_in,
                              void* d_out, int out_size, void* d_ws, size_t ws_size,
                              hipStream_t stream) {
    const float* x_mean = (const float*)d_in[0];
    const float* x_var  = (const float*)d_in[1];
    const float* A_mean = (const float*)d_in[2];
    const float* A_var  = (const float*)d_in[3];
    const float* b_mean = (const float*)d_in[4];
    const float* b_var  = (const float*)d_in[5];

    float* ymean = (float*)d_out;                  // [256,512]
    float* yvar  = (float*)d_out + 131072;         // [256,512,512]

    char* ws = (char*)d_ws;
    ushort* abt = (ushort*)ws;                     // 512 KB  (A^T tile images)
    float*  pd  = (float*)(ws + 512 * 1024);       // [256,512]
    float*  p2  = (float*)(ws + 1024 * 1024);      // [256,4,512]
    float*  xx  = (float*)(ws + 3 * 1024 * 1024);  // [256,512]

    // xbf (128 MB of bf16 tile images) aliases the yvar output region:
    // k_gemm2 consumes it fully before k_fill overwrites yvar (stream-ordered).
    ushort* xbf = (ushort*)yvar;

    k_prep_at<<<128, 256, 0, stream>>>(A_mean, abt);
    k_conv<<<1024, 256, 0, stream>>>(x_var, x_mean, xbf, xx);
    k_mean_t1<<<512, 256, 0, stream>>>(x_mean, xx, A_mean, A_var, b_mean, b_var,
                                       ymean, pd);
    k_gemm2<<<4096, 256, 0, stream>>>(xbf, abt, A_mean, p2);
    k_fill<<<16384, 256, 0, stream>>>(pd, p2, yvar);
}